// Round 10
// baseline (79.890 us; speedup 1.0000x reference)
//
#include <hip/hip_runtime.h>
#include <math.h>

// Problem constants (fixed by the reference's setup_inputs)
constexpr int B = 2, G = 8, D = 16, H = 256, W = 320;
constexpr int HW = H * W;
constexpr float EPS = 1e-5f;

typedef _Float16 half8  __attribute__((ext_vector_type(8)));
typedef _Float16 h2v    __attribute__((ext_vector_type(2)));
typedef float    f32x16 __attribute__((ext_vector_type(16)));

union H8U { half8 h; unsigned u[4]; uint4 u4; };
union H2U { h2v h; unsigned u; };

// wbuf layout (float/u32 slots):
//   [0..256)   aL1  : 64 lanes x 4 dwords (h2-packed A frag, layer1 both nets)
//   [256..512) aL2P : 64 lanes x 4 dwords (layer2 P)
//   [512..768) aL2S : 64 lanes x 4 dwords (layer2 S)
//   [768..784) b0P f32[16]; [784..792) b1P f32[8]; [792..800) w2P f32[8]
//   [800] bias2P; [801] bias2S
//   [804..812) b0S as h2 pairs (8 dwords); [812..820) b1S f32[8]; [820..828) w2S f32[8]
constexpr int WB_TOTAL = 832;

__device__ __forceinline__ float sigmoidf_(float x) {
    return 1.0f / (1.0f + __expf(-x));
}
__device__ __forceinline__ int reflect_(int i, int n) {
    return i < 0 ? -i : (i >= n ? 2 * n - 2 - i : i);
}
__device__ __forceinline__ unsigned pack2_(float a, float b) {
    H2U p; p.h.x = (_Float16)a; p.h.y = (_Float16)b; return p.u;
}

// ---------------------------------------------------------------------------
// k_prep: build MFMA-ready fragments + bias tables (BN folded).
// A-frag layout for mfma_f32_32x32x16_f16: lane l holds A[row=l&31][k=(l>>5)*8+e].
// ---------------------------------------------------------------------------
__global__ __launch_bounds__(256) void k_prep(
    const float* __restrict__ sw0, const float* __restrict__ sg0, const float* __restrict__ sb0,
    const float* __restrict__ sw1, const float* __restrict__ sg1, const float* __restrict__ sb1,
    const float* __restrict__ sw2, const float* __restrict__ sbias2,
    const float* __restrict__ pw0, const float* __restrict__ pg0, const float* __restrict__ pb0,
    const float* __restrict__ pw1, const float* __restrict__ pg1, const float* __restrict__ pb1,
    const float* __restrict__ pw2, const float* __restrict__ pbias2,
    float* __restrict__ wbuf)
{
    const int t = threadIdx.x;
    const float rs = rsqrtf(1.0f + EPS);
    unsigned* wu = (unsigned*)wbuf;

    if (t < 64) {
        // aL1: rows 0-15 = W0P (8 in-ch), rows 16-31 = W0S; K pad (k>=8) = 0
        unsigned dw[4] = {0u, 0u, 0u, 0u};
        if (t < 32) {
            const int row = t;
            #pragma unroll
            for (int j = 0; j < 4; ++j) {
                float a0, a1;
                if (row < 16) {
                    const float s = pg0[row] * rs;
                    a0 = pw0[row * 8 + 2 * j] * s; a1 = pw0[row * 8 + 2 * j + 1] * s;
                } else {
                    const float s = sg0[row - 16] * rs;
                    a0 = sw0[(row - 16) * 8 + 2 * j] * s; a1 = sw0[(row - 16) * 8 + 2 * j + 1] * s;
                }
                dw[j] = pack2_(a0, a1);
            }
        }
        #pragma unroll
        for (int j = 0; j < 4; ++j) wu[t * 4 + j] = dw[j];
    } else if (t < 128) {
        // aL2P: rows 0-7 = W1P (16 in), rows 8-31 = 0. K fully used.
        const int l = t - 64, row = l & 31, kb = (l >> 5) * 8;
        unsigned dw[4] = {0u, 0u, 0u, 0u};
        if (row < 8) {
            const float s = pg1[row] * rs;
            #pragma unroll
            for (int j = 0; j < 4; ++j)
                dw[j] = pack2_(pw1[row * 16 + kb + 2 * j] * s, pw1[row * 16 + kb + 2 * j + 1] * s);
        }
        #pragma unroll
        for (int j = 0; j < 4; ++j) wu[256 + l * 4 + j] = dw[j];
    } else if (t < 192) {
        // aL2S
        const int l = t - 128, row = l & 31, kb = (l >> 5) * 8;
        unsigned dw[4] = {0u, 0u, 0u, 0u};
        if (row < 8) {
            const float s = sg1[row] * rs;
            #pragma unroll
            for (int j = 0; j < 4; ++j)
                dw[j] = pack2_(sw1[row * 16 + kb + 2 * j] * s, sw1[row * 16 + kb + 2 * j + 1] * s);
        }
        #pragma unroll
        for (int j = 0; j < 4; ++j) wu[512 + l * 4 + j] = dw[j];
    } else {
        const int u = t - 192;
        if (u < 16)      wbuf[768 + u] = pb0[u];
        else if (u < 24) wbuf[784 + (u - 16)] = pb1[u - 16];
        else if (u < 32) wbuf[792 + (u - 24)] = pw2[u - 24];
        else if (u == 32) wbuf[800] = pbias2[0];
        else if (u == 33) wbuf[801] = sbias2[0];
        else if (u < 42) { const int j = u - 34; wu[804 + j] = pack2_(sb0[2 * j], sb0[2 * j + 1]); }
        else if (u < 50) wbuf[812 + (u - 42)] = sb1[u - 42];
        else if (u < 58) wbuf[820 + (u - 50)] = sw2[u - 50];
    }
}

// ---------------------------------------------------------------------------
// k_fused (MFMA): block = 256 thr (4 waves) x 64 px x 16 dt = 1024 items.
// Wave w owns dts [4w,4w+4), 8 groups of 32 items (one 32x32x16 MFMA each).
// L1 MFMA computes P-layer1 (rows 0-15, biased+relu) AND raw S-layer1
// pre-activations (rows 16-31, stashed in regs; vw applied later by
// linearity). L2 per net = one 32-item MFMA; B-frags built in-register via
// shfl_xor(32) half exchange. L3 = 4 FMA + shfl_xor reduce.
// ---------------------------------------------------------------------------
__global__ __launch_bounds__(256, 4) void k_fused(
    const float* __restrict__ x1,
    const float* __restrict__ depth_sample,
    const float* __restrict__ depth_min, const float* __restrict__ depth_max,
    const float* __restrict__ wbuf,
    float* __restrict__ s_out, float* __restrict__ xn_out)
{
    __shared__ float h3buf[16][64];
    __shared__ float vwbuf[64];
    __shared__ float sbuf[16][64];

    const int tid = threadIdx.x;
    const int wave = tid >> 6, lane = tid & 63;
    const bool hi = (lane & 32) != 0;
    const int c31 = lane & 31;

    const int pid0 = blockIdx.x * 64;
    const int b = pid0 / HW;
    const int p0 = pid0 - b * HW;

    const unsigned* wu = (const unsigned*)wbuf;

    // per-lane A fragments (coalesced uint4 loads)
    H8U aL1, aL2P, aL2S;
    aL1.u4  = ((const uint4*)(wu))[lane];
    aL2P.u4 = ((const uint4*)(wu + 256))[lane];
    aL2S.u4 = ((const uint4*)(wu + 512))[lane];

    const float bias2P = wbuf[800], bias2S = wbuf[801];
    const f32x16 z16 = {};
    const size_t gstride = (size_t)D * HW;     // x1 channel stride

    unsigned sst[8][4];                        // preS stash (h2 pairs), static idx

    // ---------------- Phase A: L1 (both nets) + P head ----------------
    #pragma unroll
    for (int g8 = 0; g8 < 8; ++g8) {
        const int dt = wave * 4 + (g8 >> 1);
        const int px = (g8 & 1) * 32 + c31;

        // B1 fragment: 8 channels of x for item (dt,px); lanes 32-63 = K-pad 0
        H8U bx; bx.u[0] = bx.u[1] = bx.u[2] = bx.u[3] = 0u;
        if (!hi) {
            const float* xp = x1 + ((size_t)b * G * D + dt) * HW + p0 + px;
            float v[8];
            #pragma unroll
            for (int g = 0; g < 8; ++g) v[g] = xp[g * gstride];
            #pragma unroll
            for (int j = 0; j < 4; ++j) bx.u[j] = pack2_(v[2 * j], v[2 * j + 1]);
        }

        f32x16 acc = __builtin_amdgcn_mfma_f32_32x32x16_f16(aL1.h, bx.h, z16, 0, 0, 0);

        // l1P: regs 0..7, rows = (r&3)+8*(r>>2)+4*hi; bias+relu, pack h2
        unsigned l1dw[4];
        #pragma unroll
        for (int j = 0; j < 4; ++j) {
            const int rb0 = (2 * j & 3) + 8 * (2 * j >> 2);
            const int rb1 = ((2 * j + 1) & 3) + 8 * ((2 * j + 1) >> 2);
            const float bb0 = hi ? wbuf[768 + rb0 + 4] : wbuf[768 + rb0];
            const float bb1 = hi ? wbuf[768 + rb1 + 4] : wbuf[768 + rb1];
            const float e0 = fmaxf(acc[2 * j] + bb0, 0.0f);
            const float e1 = fmaxf(acc[2 * j + 1] + bb1, 0.0f);
            l1dw[j] = pack2_(e0, e1);
        }
        // preS raw: regs 8..15 -> stash
        #pragma unroll
        for (int j = 0; j < 4; ++j) sst[g8][j] = pack2_(acc[8 + 2 * j], acc[9 + 2 * j]);

        // L2P B-frag: half-exchange so lane holds k=(hi?8:0)..+8 of its item
        const unsigned x0 = (unsigned)__shfl_xor((int)l1dw[0], 32);
        const unsigned x1_ = (unsigned)__shfl_xor((int)l1dw[1], 32);
        const unsigned x2 = (unsigned)__shfl_xor((int)l1dw[2], 32);
        const unsigned x3 = (unsigned)__shfl_xor((int)l1dw[3], 32);
        H8U b2;
        b2.u[0] = hi ? x2 : l1dw[0];
        b2.u[1] = hi ? x3 : l1dw[1];
        b2.u[2] = hi ? l1dw[2] : x0;
        b2.u[3] = hi ? l1dw[3] : x1_;

        f32x16 acc2 = __builtin_amdgcn_mfma_f32_32x32x16_f16(aL2P.h, b2.h, z16, 0, 0, 0);

        // L3P: rows o = r + 4*hi (o<8 valid)
        float part = 0.0f;
        #pragma unroll
        for (int r = 0; r < 4; ++r) {
            const float bb = hi ? wbuf[784 + r + 4] : wbuf[784 + r];
            const float ww = hi ? wbuf[792 + r + 4] : wbuf[792 + r];
            part = fmaf(fmaxf(acc2[r] + bb, 0.0f), ww, part);
        }
        part += __shfl_xor(part, 32);
        if (!hi) h3buf[dt][px] = part + bias2P;
    }
    __syncthreads();

    // ---------------- vw pass ----------------
    if (tid < 64) {
        float m = h3buf[0][tid];
        #pragma unroll
        for (int k = 1; k < 16; ++k) m = fmaxf(m, h3buf[k][tid]);
        vwbuf[tid] = sigmoidf_(m);
    }
    __syncthreads();

    // ---------------- Phase B: S net ----------------
    #pragma unroll
    for (int g8 = 0; g8 < 8; ++g8) {
        const int dt = wave * 4 + (g8 >> 1);
        const int px = (g8 & 1) * 32 + c31;
        const float vw = vwbuf[px];
        h2v vwh; vwh.x = (_Float16)vw; vwh.y = (_Float16)vw;

        const unsigned t0 = sst[g8][0], t1 = sst[g8][1], t2 = sst[g8][2], t3 = sst[g8][3];
        const unsigned y0 = (unsigned)__shfl_xor((int)t0, 32);
        const unsigned y1 = (unsigned)__shfl_xor((int)t1, 32);
        const unsigned y2 = (unsigned)__shfl_xor((int)t2, 32);
        const unsigned y3 = (unsigned)__shfl_xor((int)t3, 32);
        unsigned src[4];
        src[0] = hi ? y2 : t0;
        src[1] = hi ? y3 : t1;
        src[2] = hi ? t2 : y0;
        src[3] = hi ? t3 : y1;

        H8U b2s;
        #pragma unroll
        for (int j = 0; j < 4; ++j) {
            H2U pv; pv.u = src[j];
            H2U bb; bb.u = hi ? wu[804 + j + 4] : wu[804 + j];
            h2v val = pv.h * vwh + bb.h;           // v_pk_fma_f16
            h2v zz = {};
            val = __builtin_elementwise_max(val, zz); // packed relu
            H2U o2; o2.h = val; b2s.u[j] = o2.u;
        }

        f32x16 acc3 = __builtin_amdgcn_mfma_f32_32x32x16_f16(aL2S.h, b2s.h, z16, 0, 0, 0);

        float part = 0.0f;
        #pragma unroll
        for (int r = 0; r < 4; ++r) {
            const float bb = hi ? wbuf[812 + r + 4] : wbuf[812 + r];
            const float ww = hi ? wbuf[820 + r + 4] : wbuf[820 + r];
            part = fmaf(fmaxf(acc3[r] + bb, 0.0f), ww, part);
        }
        part += __shfl_xor(part, 32);
        if (!hi) sbuf[dt][px] = part + bias2S;
    }
    __syncthreads();

    // ---------------- final coalesced write: s, xn ----------------
    {
        const int dt = tid >> 4;
        const int px0 = (tid & 15) * 4;
        const size_t o = ((size_t)(b * D + dt)) * HW + p0 + px0;
        const float4 sv = *(const float4*)&sbuf[dt][px0];
        *(float4*)(s_out + o) = sv;
        const float inv_min = 1.0f / depth_min[b];
        const float inv_max = 1.0f / depth_max[b];
        const float rinv = 1.0f / (inv_min - inv_max);
        const float4 dsv = *(const float4*)(depth_sample + o);
        float4 xv;
        xv.x = (1.0f / dsv.x - inv_max) * rinv;
        xv.y = (1.0f / dsv.y - inv_max) * rinv;
        xv.z = (1.0f / dsv.z - inv_max) * rinv;
        xv.w = (1.0f / dsv.w - inv_max) * rinv;
        *(float4*)(xn_out + o) = xv;
    }
}

// ---------------------------------------------------------------------------
// k_score_depth: 1024 threads = 64 px x 16 depths, one depth/thread.
// Bijective XCD swizzle (nwg = 2560 = 8*320). (unchanged, ~20 us)
// ---------------------------------------------------------------------------
__global__ __launch_bounds__(1024, 8) void k_score_depth(
    const float* __restrict__ s_arr, const float* __restrict__ xn,
    const float* __restrict__ offset, const float* __restrict__ depth_sample,
    float* __restrict__ out)
{
    __shared__ float off_lds[18][64];
    __shared__ float redM[16][64];
    __shared__ float redS[16][64];
    __shared__ float redA[16][64];

    const int bid = blockIdx.x;
    const int wg = (bid & 7) * 320 + (bid >> 3);

    const int tid = threadIdx.x;
    const int pi = tid & 63;
    const int dt = tid >> 6;
    const int pg0_ = wg * 64;
    const int b = pg0_ / HW;
    const int pb0 = pg0_ - b * HW;
    const int p = pb0 + pi;
    const int h = p / W;
    const int w = p - h * W;

    const float* ob = offset + (size_t)b * 18 * HW + pb0;
    for (int idx = tid; idx < 18 * 64; idx += 1024) {
        const int s = idx >> 6, qq = idx & 63;
        off_lds[s][qq] = ob[(size_t)s * HW + qq];
    }
    __syncthreads();

    int a1s[9], a2s[9];
    {
        int ry1[3], ry2[3], cx1[3], cx2[3];
        #pragma unroll
        for (int i = 0; i < 3; ++i) {
            ry1[i] = reflect_(h + (i - 1) * 2, H) * W;
            ry2[i] = reflect_(h + (i - 1) * 4, H) * W;
            cx1[i] = reflect_(w + (i - 1) * 2, W);
            cx2[i] = reflect_(w + (i - 1) * 4, W);
        }
        #pragma unroll
        for (int s = 0; s < 9; ++s) {
            a1s[s] = ry1[s / 3] + cx1[s % 3];
            a2s[s] = ry2[s / 3] + cx2[s % 3];
        }
    }

    const size_t bbase = (size_t)b * D * HW;
    const float* sd = s_arr + bbase + (size_t)dt * HW;
    const float* xd = xn + bbase + (size_t)dt * HW;

    float accs = 0.0f, accx = 0.0f;
    #pragma unroll
    for (int s = 0; s < 9; ++s) {
        const float w1 = off_lds[s + 9][pi];
        const float w2 = off_lds[s][pi];
        accs += 0.5f * (w1 * sd[a1s[s]] + w2 * sd[a2s[s]]);
        accx += 0.5f * (w1 * xd[a1s[s]] + w2 * xd[a2s[s]]);
    }
    const float xc = xd[p];
    const float diff = fminf(fabsf(accx - xc) * 40.0f, 4.0f);
    const float dwv = sigmoidf_((2.0f - diff) * 2.0f);
    const float score = accs * dwv;
    const float dsv = depth_sample[bbase + (size_t)dt * HW + p];

    redM[dt][pi] = score;
    __syncthreads();
    float m = redM[0][pi];
    #pragma unroll
    for (int k = 1; k < 16; ++k) m = fmaxf(m, redM[k][pi]);

    const float e = __expf(score - m);
    redS[dt][pi] = e;
    redA[dt][pi] = dsv * e;
    __syncthreads();

    if (dt == 0) {
        float sum = 0.0f, acc = 0.0f;
        #pragma unroll
        for (int k = 0; k < 16; ++k) { sum += redS[k][pi]; acc += redA[k][pi]; }
        out[pg0_ + pi] = acc / sum;
    }
}

// ---------------------------------------------------------------------------
extern "C" void kernel_launch(void* const* d_in, const int* in_sizes, int n_in,
                              void* d_out, int out_size, void* d_ws, size_t ws_size,
                              hipStream_t stream)
{
    const float* x1           = (const float*)d_in[0];
    const float* offset       = (const float*)d_in[1];
    const float* depth_sample = (const float*)d_in[2];
    const float* depth_min    = (const float*)d_in[3];
    const float* depth_max    = (const float*)d_in[4];
    const float* s_w0 = (const float*)d_in[5];
    const float* s_g0 = (const float*)d_in[6];
    const float* s_b0 = (const float*)d_in[7];
    const float* s_w1 = (const float*)d_in[8];
    const float* s_g1 = (const float*)d_in[9];
    const float* s_b1 = (const float*)d_in[10];
    const float* s_w2 = (const float*)d_in[11];
    const float* s_bias2 = (const float*)d_in[12];
    const float* p_w0 = (const float*)d_in[13];
    const float* p_g0 = (const float*)d_in[14];
    const float* p_b0 = (const float*)d_in[15];
    const float* p_w1 = (const float*)d_in[16];
    const float* p_g1 = (const float*)d_in[17];
    const float* p_b1 = (const float*)d_in[18];
    const float* p_w2 = (const float*)d_in[19];
    const float* p_bias2 = (const float*)d_in[20];

    float* s_arr = (float*)d_ws;                         // B*D*HW
    float* xn    = s_arr + (size_t)B * D * HW;           // B*D*HW
    float* wbuf  = xn + (size_t)B * D * HW;              // WB_TOTAL floats

    k_prep<<<1, 256, 0, stream>>>(
        s_w0, s_g0, s_b0, s_w1, s_g1, s_b1, s_w2, s_bias2,
        p_w0, p_g0, p_b0, p_w1, p_g1, p_b1, p_w2, p_bias2, wbuf);

    k_fused<<<(B * HW) / 64, 256, 0, stream>>>(
        x1, depth_sample, depth_min, depth_max,
        wbuf, s_arr, xn);

    k_score_depth<<<(B * HW) / 64, 1024, 0, stream>>>(
        s_arr, xn, offset, depth_sample, (float*)d_out);
}